// Round 2
// baseline (122.609 us; speedup 1.0000x reference)
//
#include <hip/hip_runtime.h>
#include <hip/hip_bf16.h>

#define H_    32
#define HKV_  8
#define D_    128
#define HID_  4096
#define S_    32768
#define NQKV  6144        // 4096 + 1024 + 1024
#define SPLIT 64          // split-K for the GEMVs
#define CHUNK 512         // tokens per attention block
#define NCHUNK (S_ / CHUNK)   // 64
#define SCALE_ 0.08838834764831843f  // 1/sqrt(128)

// workspace layout (float offsets)
#define WS_QKV_PART 0                      // [SPLIT][NQKV]        393216
#define WS_QKV      393216                 // [NQKV]               6144
#define WS_SCORES   399360                 // [H][S]               1048576
#define WS_BLOCKMAX 1447936                // [H][NCHUNK]          2048
#define WS_M        1449984                // [H]                  32
#define WS_PCUR     1450016                // [H]                  32
#define WS_PV_PART  1450048                // [NCHUNK][HKV][4][D]  1048576
#define WS_DSUM     2498624                // [NCHUNK][HKV][4]     2048
#define WS_ATTN     2500672                // [H*D]                4096
#define WS_OPART    2504768                // [SPLIT][HID]         262144
// total ~2.77M floats = ~11 MB

// ---------------- kernel 1: QKV GEMV split-K partials ----------------
__global__ __launch_bounds__(256) void k_qkv_part(
    const float* __restrict__ hid, const float* __restrict__ Wq,
    const float* __restrict__ Wk, const float* __restrict__ Wv,
    float* __restrict__ part)
{
    const int j0 = blockIdx.x * 1024 + threadIdx.x * 4;   // 6 col-blocks of 1024
    const int i0 = blockIdx.y * (HID_ / SPLIT);           // 64-row chunk
    __shared__ float hs[HID_ / SPLIT];
    if (threadIdx.x < HID_ / SPLIT) hs[threadIdx.x] = hid[i0 + threadIdx.x];
    __syncthreads();

    const float* W; int ldw; int col;
    if (j0 < 4096)       { W = Wq; ldw = 4096; col = j0; }
    else if (j0 < 5120)  { W = Wk; ldw = 1024; col = j0 - 4096; }
    else                 { W = Wv; ldw = 1024; col = j0 - 5120; }

    float4 acc = {0.f, 0.f, 0.f, 0.f};
    const float* p = W + (size_t)i0 * ldw + col;
    #pragma unroll 8
    for (int i = 0; i < HID_ / SPLIT; ++i) {
        const float4 wv = *(const float4*)(p + (size_t)i * ldw);
        const float h = hs[i];
        acc.x += h * wv.x; acc.y += h * wv.y; acc.z += h * wv.z; acc.w += h * wv.w;
    }
    *(float4*)&part[(size_t)blockIdx.y * NQKV + j0] = acc;
}

// ---------------- kernel 2: reduce partials + RoPE ----------------
__global__ __launch_bounds__(256) void k_qkv_reduce(
    const float* __restrict__ part, const float* __restrict__ cosv,
    const float* __restrict__ sinv, float* __restrict__ qkv)
{
    const int j = blockIdx.x * 256 + threadIdx.x;  // 24 blocks
    float s = 0.f;
    #pragma unroll 8
    for (int k = 0; k < SPLIT; ++k) s += part[(size_t)k * NQKV + j];
    __shared__ float buf[256];
    buf[threadIdx.x] = s;
    __syncthreads();
    float out = s;
    if (j < 5120) {  // q and k get RoPE; v passes through
        const int d = j & 127;
        const float rot = (d < 64) ? -buf[threadIdx.x + 64] : buf[threadIdx.x - 64];
        out = s * cosv[d] + rot * sinv[d];
    }
    qkv[j] = out;
}

// ---------------- kernel 3: past scores + per-chunk max ----------------
// block = 256 thr (4 waves); wave handles 8 tokens/iter; lane = t*8+j,
// lane covers d-slices {(j+8k)*4..+3, k=0..3} (128B-coalesced int4 loads)
__global__ __launch_bounds__(256) void k_scores(
    const int* __restrict__ kqx, const float* __restrict__ kscale,
    const float* __restrict__ qkv, float* __restrict__ scores,
    float* __restrict__ blockmax)
{
    const int kh = blockIdx.y;
    const int c0 = blockIdx.x * CHUNK;
    const int tid = threadIdx.x;
    const int w = tid >> 6, l = tid & 63;
    const int t = l >> 3, j = l & 7;

    float4 qf[4][4];
    #pragma unroll
    for (int g = 0; g < 4; ++g) {
        #pragma unroll
        for (int k = 0; k < 4; ++k)
            qf[g][k] = *(const float4*)&qkv[(kh * 4 + g) * D_ + (j + 8 * k) * 4];
    }

    float mx[4] = {-1e30f, -1e30f, -1e30f, -1e30f};

    for (int it = 0; it < CHUNK / 32; ++it) {
        const int tok = c0 + it * 32 + w * 8 + t;
        const int* kp = kqx + ((size_t)tok * HKV_ + kh) * D_;
        float dot[4] = {0.f, 0.f, 0.f, 0.f};
        #pragma unroll
        for (int k = 0; k < 4; ++k) {
            const int4 kv = *(const int4*)(kp + (j + 8 * k) * 4);
            const float f0 = (float)kv.x, f1 = (float)kv.y;
            const float f2 = (float)kv.z, f3 = (float)kv.w;
            #pragma unroll
            for (int g = 0; g < 4; ++g)
                dot[g] += f0 * qf[g][k].x + f1 * qf[g][k].y +
                          f2 * qf[g][k].z + f3 * qf[g][k].w;
        }
        #pragma unroll
        for (int m = 1; m < 8; m <<= 1) {
            #pragma unroll
            for (int g = 0; g < 4; ++g) dot[g] += __shfl_xor(dot[g], m, 64);
        }
        const float sc = kscale[tok * HKV_ + kh] * SCALE_;
        #pragma unroll
        for (int g = 0; g < 4; ++g) { dot[g] *= sc; mx[g] = fmaxf(mx[g], dot[g]); }
        if (j < 4) scores[(size_t)(kh * 4 + j) * S_ + tok] = dot[j];
    }
    // reduce max across token-slots (j-group lanes hold identical values)
    #pragma unroll
    for (int m = 8; m < 64; m <<= 1) {
        #pragma unroll
        for (int g = 0; g < 4; ++g) mx[g] = fmaxf(mx[g], __shfl_xor(mx[g], m, 64));
    }
    __shared__ float wmax[4][4];
    if (l == 0) {
        for (int g = 0; g < 4; ++g) wmax[w][g] = mx[g];
    }
    __syncthreads();
    if (tid < 4) {
        const float m0 = fmaxf(fmaxf(wmax[0][tid], wmax[1][tid]),
                               fmaxf(wmax[2][tid], wmax[3][tid]));
        blockmax[(kh * 4 + tid) * NCHUNK + blockIdx.x] = m0;
    }
}

// ---------------- kernel 4: current-token score, global max, p_cur ----------------
__global__ __launch_bounds__(256) void k_finalize(
    const float* __restrict__ qkv, const float* __restrict__ blockmax,
    float* __restrict__ M, float* __restrict__ pcur)
{
    __shared__ float scur_s[H_];
    const int tid = threadIdx.x;
    const int h = tid >> 3, j = tid & 7;
    const float* q = qkv + h * D_;
    const float* k = qkv + 4096 + (h >> 2) * D_;
    float p = 0.f;
    #pragma unroll
    for (int e = 0; e < 16; ++e) { const int d = j * 16 + e; p += q[d] * k[d]; }
    #pragma unroll
    for (int m = 1; m < 8; m <<= 1) p += __shfl_xor(p, m, 64);
    if (j == 0) scur_s[h] = p * SCALE_;
    __syncthreads();
    if (tid < H_) {
        float m0 = scur_s[tid];
        for (int c = 0; c < NCHUNK; ++c)
            m0 = fmaxf(m0, blockmax[tid * NCHUNK + c]);
        M[tid] = m0;
        pcur[tid] = __expf(scur_s[tid] - m0);
    }
}

// ---------------- kernel 5: PV partials (flash-decode) ----------------
__global__ __launch_bounds__(256) void k_pv(
    const int* __restrict__ vqx, const float* __restrict__ vscale,
    const float* __restrict__ scores, const float* __restrict__ M,
    float* __restrict__ pv_part, float* __restrict__ dsum_part)
{
    const int kh = blockIdx.y;
    const int c0 = blockIdx.x * CHUNK;
    const int tid = threadIdx.x;
    const int w = tid >> 6, l = tid & 63;
    const int t = l >> 3, j = l & 7;

    float Mh[4];
    #pragma unroll
    for (int g = 0; g < 4; ++g) Mh[g] = M[kh * 4 + g];

    float4 acc[4][4];
    #pragma unroll
    for (int g = 0; g < 4; ++g) {
        #pragma unroll
        for (int k = 0; k < 4; ++k) acc[g][k] = make_float4(0.f, 0.f, 0.f, 0.f);
    }
    float ds[4] = {0.f, 0.f, 0.f, 0.f};

    for (int it = 0; it < CHUNK / 32; ++it) {
        const int tok = c0 + it * 32 + w * 8 + t;
        const int* vp = vqx + ((size_t)tok * HKV_ + kh) * D_;
        float wgt[4];
        #pragma unroll
        for (int g = 0; g < 4; ++g)
            wgt[g] = __expf(scores[(size_t)(kh * 4 + g) * S_ + tok] - Mh[g]);
        #pragma unroll
        for (int g = 0; g < 4; ++g) ds[g] += wgt[g];
        const float vs = vscale[tok * HKV_ + kh];
        #pragma unroll
        for (int g = 0; g < 4; ++g) wgt[g] *= vs;
        #pragma unroll
        for (int k = 0; k < 4; ++k) {
            const int4 vv = *(const int4*)(vp + (j + 8 * k) * 4);
            const float f0 = (float)vv.x, f1 = (float)vv.y;
            const float f2 = (float)vv.z, f3 = (float)vv.w;
            #pragma unroll
            for (int g = 0; g < 4; ++g) {
                acc[g][k].x += wgt[g] * f0; acc[g][k].y += wgt[g] * f1;
                acc[g][k].z += wgt[g] * f2; acc[g][k].w += wgt[g] * f3;
            }
        }
    }
    // sum acc across the 8 token-slots (masks 8,16,32 flip t bits)
    #pragma unroll
    for (int m = 8; m < 64; m <<= 1) {
        #pragma unroll
        for (int g = 0; g < 4; ++g) {
            #pragma unroll
            for (int k = 0; k < 4; ++k) {
                acc[g][k].x += __shfl_xor(acc[g][k].x, m, 64);
                acc[g][k].y += __shfl_xor(acc[g][k].y, m, 64);
                acc[g][k].z += __shfl_xor(acc[g][k].z, m, 64);
                acc[g][k].w += __shfl_xor(acc[g][k].w, m, 64);
            }
        }
        #pragma unroll
        for (int g = 0; g < 4; ++g) ds[g] += __shfl_xor(ds[g], m, 64);
    }
    __shared__ float lacc[4][8][64];   // [wave][j][g*16 + k*4 + e]
    __shared__ float ldss[4][4];       // [wave][g]
    if (t == 0) {
        #pragma unroll
        for (int g = 0; g < 4; ++g) {
            #pragma unroll
            for (int k = 0; k < 4; ++k)
                *(float4*)&lacc[w][j][g * 16 + k * 4] = acc[g][k];
        }
    }
    if (l == 0) {
        for (int g = 0; g < 4; ++g) ldss[w][g] = ds[g];
    }
    __syncthreads();
    for (int idx = tid; idx < 512; idx += 256) {
        const int g = idx >> 7, d = idx & 127;
        const int e = d & 3, jk = d >> 2, jj = jk & 7, kk = jk >> 3;
        const float v = lacc[0][jj][g * 16 + kk * 4 + e] + lacc[1][jj][g * 16 + kk * 4 + e] +
                        lacc[2][jj][g * 16 + kk * 4 + e] + lacc[3][jj][g * 16 + kk * 4 + e];
        pv_part[(((size_t)blockIdx.x * HKV_ + kh) * 4 + g) * D_ + d] = v;
    }
    if (tid < 4)
        dsum_part[(blockIdx.x * HKV_ + kh) * 4 + tid] =
            ldss[0][tid] + ldss[1][tid] + ldss[2][tid] + ldss[3][tid];
}

// ---------------- kernel 6: combine partials + current token ----------------
__global__ __launch_bounds__(256) void k_combine(
    const float* __restrict__ pv_part, const float* __restrict__ dsum_part,
    const float* __restrict__ pcur, const float* __restrict__ qkv,
    float* __restrict__ attn)
{
    const int idx = blockIdx.x * 256 + threadIdx.x;  // 16 blocks → 4096
    const int h = idx >> 7, d = idx & 127;
    const int kh = h >> 2, g = h & 3;
    float pv = 0.f;
    for (int c = 0; c < NCHUNK; ++c)
        pv += pv_part[(((size_t)c * HKV_ + kh) * 4 + g) * D_ + d];
    float dsum = 0.f;
    for (int c = 0; c < NCHUNK; ++c)
        dsum += dsum_part[(c * HKV_ + kh) * 4 + g];
    const float pc = pcur[h];
    const float vcur = qkv[5120 + kh * D_ + d];
    attn[idx] = (pv + pc * vcur) / (dsum + pc);
}

// ---------------- kernel 7: output GEMV split-K partials ----------------
__global__ __launch_bounds__(256) void k_out_part(
    const float* __restrict__ attn, const float* __restrict__ Wo,
    float* __restrict__ opart)
{
    const int j0 = blockIdx.x * 1024 + threadIdx.x * 4;  // 4 col-blocks
    const int i0 = blockIdx.y * (HID_ / SPLIT);
    __shared__ float hs[HID_ / SPLIT];
    if (threadIdx.x < HID_ / SPLIT) hs[threadIdx.x] = attn[i0 + threadIdx.x];
    __syncthreads();
    float4 acc = {0.f, 0.f, 0.f, 0.f};
    const float* p = Wo + (size_t)i0 * HID_ + j0;
    #pragma unroll 8
    for (int i = 0; i < HID_ / SPLIT; ++i) {
        const float4 wv = *(const float4*)(p + (size_t)i * HID_);
        const float h = hs[i];
        acc.x += h * wv.x; acc.y += h * wv.y; acc.z += h * wv.z; acc.w += h * wv.w;
    }
    *(float4*)&opart[(size_t)blockIdx.y * HID_ + j0] = acc;
}

// ---------------- kernel 8: reduce output partials ----------------
__global__ __launch_bounds__(256) void k_out_reduce(
    const float* __restrict__ opart, float* __restrict__ out)
{
    const int j = blockIdx.x * 256 + threadIdx.x;  // 16 blocks
    float s = 0.f;
    #pragma unroll 8
    for (int k = 0; k < SPLIT; ++k) s += opart[(size_t)k * HID_ + j];
    out[j] = s;
}

extern "C" void kernel_launch(void* const* d_in, const int* in_sizes, int n_in,
                              void* d_out, int out_size, void* d_ws, size_t ws_size,
                              hipStream_t stream) {
    const float* hid    = (const float*)d_in[0];
    const int*   kqx    = (const int*)d_in[1];
    const float* kscale = (const float*)d_in[2];
    const int*   vqx    = (const int*)d_in[3];
    const float* vscale = (const float*)d_in[4];
    const float* cosv   = (const float*)d_in[5];
    const float* sinv   = (const float*)d_in[6];
    const float* Wq     = (const float*)d_in[7];
    const float* Wk     = (const float*)d_in[8];
    const float* Wv     = (const float*)d_in[9];
    const float* Wo     = (const float*)d_in[10];
    float* ws  = (float*)d_ws;
    float* out = (float*)d_out;

    k_qkv_part  <<<dim3(6, SPLIT), 256, 0, stream>>>(hid, Wq, Wk, Wv, ws + WS_QKV_PART);
    k_qkv_reduce<<<dim3(24),       256, 0, stream>>>(ws + WS_QKV_PART, cosv, sinv, ws + WS_QKV);
    k_scores    <<<dim3(NCHUNK, HKV_), 256, 0, stream>>>(kqx, kscale, ws + WS_QKV,
                                                         ws + WS_SCORES, ws + WS_BLOCKMAX);
    k_finalize  <<<dim3(1),        256, 0, stream>>>(ws + WS_QKV, ws + WS_BLOCKMAX,
                                                     ws + WS_M, ws + WS_PCUR);
    k_pv        <<<dim3(NCHUNK, HKV_), 256, 0, stream>>>(vqx, vscale, ws + WS_SCORES,
                                                         ws + WS_M, ws + WS_PV_PART, ws + WS_DSUM);
    k_combine   <<<dim3(16),       256, 0, stream>>>(ws + WS_PV_PART, ws + WS_DSUM,
                                                     ws + WS_PCUR, ws + WS_QKV, ws + WS_ATTN);
    k_out_part  <<<dim3(4, SPLIT), 256, 0, stream>>>(ws + WS_ATTN, Wo, ws + WS_OPART);
    k_out_reduce<<<dim3(16),       256, 0, stream>>>(ws + WS_OPART, out);
}